// Round 4
// baseline (2419.566 us; speedup 1.0000x reference)
//
#include <hip/hip_runtime.h>

#define T_STEPS 512
#define B_ENV   256
#define D_IN    64
#define H_DIM   128
#define G4      512   // 4*H gate rows

typedef _Float16 h2v __attribute__((ext_vector_type(2)));
typedef _Float16 h8v __attribute__((ext_vector_type(8)));
typedef float    f4v __attribute__((ext_vector_type(4)));

__device__ __forceinline__ float dot2(h2v a, h2v b, float c) {
#if __has_builtin(__builtin_amdgcn_fdot2)
    return __builtin_amdgcn_fdot2(a, b, c, false);
#else
    return c + (float)a.x * (float)b.x + (float)a.y * (float)b.y;
#endif
}

__device__ __forceinline__ h2v pack16(float a, float b) {
#if __has_builtin(__builtin_amdgcn_cvt_pkrtz)
    union { __fp16 __attribute__((ext_vector_type(2))) r; h2v h; } u;
    u.r = __builtin_amdgcn_cvt_pkrtz(a, b);
    return u.h;
#else
    h2v p; p.x = (_Float16)a; p.y = (_Float16)b; return p;
#endif
}

__device__ __forceinline__ float fast_rcp(float x) {
#if __has_builtin(__builtin_amdgcn_rcpf)
    return __builtin_amdgcn_rcpf(x);
#else
    return 1.0f / x;
#endif
}
__device__ __forceinline__ float sigm(float x)   { return fast_rcp(1.0f + __expf(-x)); }
__device__ __forceinline__ float tanh_f(float x) { float e = __expf(2.0f * x); return 1.0f - 2.0f * fast_rcp(e + 1.0f); }

// Barrier that drains LDS ops only — global loads/stores stay in flight
// (unlike __syncthreads(), which emits s_waitcnt vmcnt(0) and serializes
// the prefetch latency into every step).
__device__ __forceinline__ void sync_lds() {
    asm volatile("s_waitcnt lgkmcnt(0)" ::: "memory");
    __builtin_amdgcn_s_barrier();
    asm volatile("" ::: "memory");
}

// Scan kernel: one block per env. 768 threads = 12 waves (3/SIMD, VGPR cap 170).
//   tid [0,512):  gate threads. Quad (j=tid>>2, qq=tid&3) owns h-index j.
//                 Thread holds k-quarter qq of all 4 W_hh rows {j,128+j,256+j,384+j}
//                 (64 h2v regs). Per step: partial dots -> quad allreduce (2x
//                 shfl_xor DPP) -> activations + cell update in-lane -> qq==0
//                 writes h (f16, double-buffered LDS) + raw h_t (f32) to d_out.
//   tid [512,768): xg threads. 2 rows of W_ih in regs. Consume x_reg (prefetched
//                 last step), write xg_{t+1} to LDS, issue x[t+2] loads.
// ONE raw barrier per step; x/done prefetch latency hidden across steps.
__global__ __launch_bounds__(768, 3)
void ppo_lstm_scan(const float* __restrict__ x,      // [T,B,D]
                   const float* __restrict__ done,   // [T,B]
                   const float* __restrict__ h0,     // [B,H]
                   const float* __restrict__ c0,     // [B,H]
                   const float* __restrict__ W_ih,   // [4H,D]
                   const float* __restrict__ b_ih,   // [4H]
                   const float* __restrict__ W_hh,   // [4H,H]
                   const float* __restrict__ b_hh,   // [4H]
                   float* __restrict__ hs)           // [T,B,H] = d_out (raw h)
{
    const int b   = blockIdx.x;
    const int tid = threadIdx.x;
    const int j   = tid >> 2;   // h-index for gate threads
    const int qq  = tid & 3;    // k-quarter

    __shared__ h2v   h_lds[2][H_DIM / 2];   // double-buffered h (f16)
    __shared__ float xg_lds[2][G4];         // double-buffered x-projection

    h2v  w[64];
    f4v  xr[16];                 // x-row prefetch (xg threads)
    float bias = 0.f, bias2 = 0.f, c_reg = 0.f;

    if (tid < G4) {
        // 4 gate rows of W_hh, k-quarter qq
        #pragma unroll
        for (int g = 0; g < 4; ++g) {
            const float* wr = W_hh + (size_t)(g * H_DIM + j) * H_DIM + qq * 32;
            #pragma unroll
            for (int c = 0; c < 16; ++c)
                w[g * 16 + c] = pack16(wr[2 * c], wr[2 * c + 1]);
        }
        c_reg = c0[b * H_DIM + j];   // replicated across the quad
    } else {
        const int q = tid - G4;
        const float* wr0 = W_ih + (size_t)q * D_IN;
        const float* wr1 = W_ih + (size_t)(q + 256) * D_IN;
        #pragma unroll
        for (int c = 0; c < 32; ++c) w[c]      = pack16(wr0[2 * c], wr0[2 * c + 1]);
        #pragma unroll
        for (int c = 0; c < 32; ++c) w[32 + c] = pack16(wr1[2 * c], wr1[2 * c + 1]);
        bias  = b_ih[q]       + b_hh[q];
        bias2 = b_ih[q + 256] + b_hh[q + 256];
    }

    // stage h0 (buf 0), compute xg_0, prefetch x[1]
    if (tid < 64) {
        const float* hp = h0 + b * H_DIM;
        h_lds[0][tid] = pack16(hp[2 * tid], hp[2 * tid + 1]);
    }
    float dcur = done[b];   // done[0,b]
    if (tid >= G4) {
        const int q = tid - G4;
        const float* xp = x + (size_t)b * D_IN;
        float s0 = 0.f, s1 = 0.f;
        #pragma unroll
        for (int c4 = 0; c4 < 16; ++c4) {
            f4v xx = *reinterpret_cast<const f4v*>(xp + 4 * c4);
            h2v xa = pack16(xx.x, xx.y), xb = pack16(xx.z, xx.w);
            s0 = dot2(w[2 * c4], xa, s0);      s0 = dot2(w[2 * c4 + 1], xb, s0);
            s1 = dot2(w[32 + 2 * c4], xa, s1); s1 = dot2(w[32 + 2 * c4 + 1], xb, s1);
        }
        xg_lds[0][q]       = s0 + bias;
        xg_lds[0][q + 256] = s1 + bias2;
        const float* xp1 = x + ((size_t)B_ENV + b) * D_IN;
        #pragma unroll
        for (int i = 0; i < 16; ++i)
            xr[i] = *reinterpret_cast<const f4v*>(xp1 + 4 * i);
    }
    __syncthreads();   // one full sync before the loop is fine

    for (int t = 0; t < T_STEPS; ++t) {
        const int   tn    = (t + 1 < T_STEPS) ? (t + 1) : t;
        const float dnext = done[tn * B_ENV + b];        // consumed next iter
        const float dmask = 1.0f - dcur;
        const int   rb    = t & 1, wb = rb ^ 1;

        if (tid < G4) {
            float p0 = 0.f, p1 = 0.f, p2 = 0.f, p3 = 0.f;
            const h8v* hp8 = reinterpret_cast<const h8v*>(&h_lds[rb][qq * 16]);
            #pragma unroll
            for (int c4 = 0; c4 < 4; ++c4) {
                union { h8v v; h2v p[4]; } u;
                u.v = hp8[c4];
                #pragma unroll
                for (int pp = 0; pp < 4; ++pp) {
                    p0 = dot2(w[      4 * c4 + pp], u.p[pp], p0);
                    p1 = dot2(w[16 +  4 * c4 + pp], u.p[pp], p1);
                    p2 = dot2(w[32 +  4 * c4 + pp], u.p[pp], p2);
                    p3 = dot2(w[48 +  4 * c4 + pp], u.p[pp], p3);
                }
            }
            // quad allreduce (lanes j*4..j*4+3): 2 DPP levels
            p0 += __shfl_xor(p0, 1); p0 += __shfl_xor(p0, 2);
            p1 += __shfl_xor(p1, 1); p1 += __shfl_xor(p1, 2);
            p2 += __shfl_xor(p2, 1); p2 += __shfl_xor(p2, 2);
            p3 += __shfl_xor(p3, 1); p3 += __shfl_xor(p3, 2);
            const float gi = xg_lds[rb][          j] + dmask * p0;
            const float gf = xg_lds[rb][H_DIM   + j] + dmask * p1;
            const float gg = xg_lds[rb][2*H_DIM + j] + dmask * p2;
            const float go = xg_lds[rb][3*H_DIM + j] + dmask * p3;
            const float cn = sigm(gf) * (c_reg * dmask) + sigm(gi) * tanh_f(gg);
            c_reg = cn;                       // replicated, bit-identical in quad
            const float hn = sigm(go) * tanh_f(cn);
            if (qq == 0) {
                reinterpret_cast<_Float16*>(h_lds[wb])[j] = (_Float16)hn;
                hs[((size_t)t * B_ENV + b) * H_DIM + j] = hn;   // store in flight
            }
        } else if (t + 1 < T_STEPS) {
            const int q = tid - G4;
            float s0 = 0.f, s1 = 0.f;
            #pragma unroll
            for (int c4 = 0; c4 < 16; ++c4) {
                f4v xx = xr[c4];
                h2v xa = pack16(xx.x, xx.y), xb = pack16(xx.z, xx.w);
                s0 = dot2(w[2 * c4], xa, s0);      s0 = dot2(w[2 * c4 + 1], xb, s0);
                s1 = dot2(w[32 + 2 * c4], xa, s1); s1 = dot2(w[32 + 2 * c4 + 1], xb, s1);
            }
            xg_lds[wb][q]       = s0 + bias;
            xg_lds[wb][q + 256] = s1 + bias2;
            const int t2 = (t + 2 < T_STEPS) ? (t + 2) : (T_STEPS - 1);
            const float* xp2 = x + ((size_t)t2 * B_ENV + b) * D_IN;
            #pragma unroll
            for (int i = 0; i < 16; ++i)
                xr[i] = *reinterpret_cast<const f4v*>(xp2 + 4 * i);   // in flight
        }
        sync_lds();   // lgkmcnt only — global loads/stores NOT drained
        dcur = dnext;
    }
}

// In-place row projection: out[r,:] = out_row @ W_hid^T + b_hid.
// 1024 blocks x 256 threads; block owns 128 rows (disjoint -> in-place safe).
// W_hid + h rows staged in LDS as f16 pairs (pad 68 -> 16B aligned, <=2-way
// bank aliasing); 8x8 register tile per thread via b128 LDS reads.
#define PADK 68
__global__ __launch_bounds__(256)
void ppo_proj(const float* __restrict__ W_hid,   // [H,H]
              const float* __restrict__ b_hid,   // [H]
              float* __restrict__ out)           // [T*B, H] in-place
{
    __shared__ h2v wl[H_DIM][PADK];
    __shared__ h2v hl[H_DIM][PADK];
    const int tid = threadIdx.x;
    const int rg  = tid >> 4;    // 16 row-groups * 8 rows
    const int cg  = tid & 15;    // 16 col-groups, cols cg + 16*jj

    const size_t r0 = (size_t)blockIdx.x * H_DIM;

    #pragma unroll
    for (int i = 0; i < 16; ++i) {            // stage W_hid: 4096 f4v
        const int idx = tid + 256 * i;
        const int r = idx >> 5, cc = idx & 31;
        f4v v = *reinterpret_cast<const f4v*>(W_hid + 4 * (size_t)idx);
        wl[r][2 * cc]     = pack16(v.x, v.y);
        wl[r][2 * cc + 1] = pack16(v.z, v.w);
    }
    #pragma unroll
    for (int i = 0; i < 16; ++i) {            // stage 128 h rows: 4096 f4v
        const int idx = tid + 256 * i;
        const int r = idx >> 5, cc = idx & 31;
        f4v v = *reinterpret_cast<const f4v*>(out + (r0 + r) * H_DIM + 4 * cc);
        hl[r][2 * cc]     = pack16(v.x, v.y);
        hl[r][2 * cc + 1] = pack16(v.z, v.w);
    }
    float bcol[8];
    #pragma unroll
    for (int jj = 0; jj < 8; ++jj) bcol[jj] = b_hid[cg + 16 * jj];
    __syncthreads();

    float acc[8][8];
    #pragma unroll
    for (int i = 0; i < 8; ++i)
        #pragma unroll
        for (int jj = 0; jj < 8; ++jj) acc[i][jj] = 0.f;

    for (int kq = 0; kq < 16; ++kq) {         // k in b128 quads (4 h2v)
        union { h8v v; h2v p[4]; } hv[8], wv[8];
        #pragma unroll
        for (int i = 0; i < 8; ++i)
            hv[i].v = *reinterpret_cast<const h8v*>(&hl[rg * 8 + i][4 * kq]);
        #pragma unroll
        for (int jj = 0; jj < 8; ++jj)
            wv[jj].v = *reinterpret_cast<const h8v*>(&wl[cg + 16 * jj][4 * kq]);
        #pragma unroll
        for (int i = 0; i < 8; ++i)
            #pragma unroll
            for (int jj = 0; jj < 8; ++jj) {
                acc[i][jj] = dot2(hv[i].p[0], wv[jj].p[0], acc[i][jj]);
                acc[i][jj] = dot2(hv[i].p[1], wv[jj].p[1], acc[i][jj]);
                acc[i][jj] = dot2(hv[i].p[2], wv[jj].p[2], acc[i][jj]);
                acc[i][jj] = dot2(hv[i].p[3], wv[jj].p[3], acc[i][jj]);
            }
    }

    #pragma unroll
    for (int i = 0; i < 8; ++i)
        #pragma unroll
        for (int jj = 0; jj < 8; ++jj)
            out[(r0 + rg * 8 + i) * H_DIM + cg + 16 * jj] = acc[i][jj] + bcol[jj];
}

extern "C" void kernel_launch(void* const* d_in, const int* in_sizes, int n_in,
                              void* d_out, int out_size, void* d_ws, size_t ws_size,
                              hipStream_t stream) {
    const float* x     = (const float*)d_in[0];
    const float* done  = (const float*)d_in[1];
    const float* h0    = (const float*)d_in[2];
    const float* c0    = (const float*)d_in[3];
    const float* W_ih  = (const float*)d_in[4];
    const float* b_ih  = (const float*)d_in[5];
    const float* W_hh  = (const float*)d_in[6];
    const float* b_hh  = (const float*)d_in[7];
    const float* W_hid = (const float*)d_in[8];
    const float* b_hid = (const float*)d_in[9];
    float* out = (float*)d_out;
    (void)d_ws; (void)ws_size; (void)out_size; (void)n_in; (void)in_sizes;

    hipLaunchKernelGGL(ppo_lstm_scan, dim3(B_ENV), dim3(768), 0, stream,
                       x, done, h0, c0, W_ih, b_ih, W_hh, b_hh, out);
    hipLaunchKernelGGL(ppo_proj, dim3((T_STEPS * B_ENV) / H_DIM), dim3(256), 0, stream,
                       W_hid, b_hid, out);
}

// Round 5
// 554.467 us; speedup vs baseline: 4.3638x; 4.3638x over previous
//
#include <hip/hip_runtime.h>

#define T_STEPS 512
#define B_ENV   256
#define D_IN    64
#define H_DIM   128
#define G4      512   // 4*H gate rows

typedef _Float16 h2v __attribute__((ext_vector_type(2)));
typedef _Float16 h8v __attribute__((ext_vector_type(8)));
typedef float    f4v __attribute__((ext_vector_type(4)));

__device__ __forceinline__ float dot2(h2v a, h2v b, float c) {
#if __has_builtin(__builtin_amdgcn_fdot2)
    return __builtin_amdgcn_fdot2(a, b, c, false);
#else
    return c + (float)a.x * (float)b.x + (float)a.y * (float)b.y;
#endif
}

__device__ __forceinline__ h2v pack16(float a, float b) {
#if __has_builtin(__builtin_amdgcn_cvt_pkrtz)
    union { __fp16 __attribute__((ext_vector_type(2))) r; h2v h; } u;
    u.r = __builtin_amdgcn_cvt_pkrtz(a, b);
    return u.h;
#else
    h2v p; p.x = (_Float16)a; p.y = (_Float16)b; return p;
#endif
}

__device__ __forceinline__ float fast_rcp(float x) {
#if __has_builtin(__builtin_amdgcn_rcpf)
    return __builtin_amdgcn_rcpf(x);
#else
    return 1.0f / x;
#endif
}
__device__ __forceinline__ float sigm(float x)   { return fast_rcp(1.0f + __expf(-x)); }
__device__ __forceinline__ float tanh_f(float x) { float e = __expf(2.0f * x); return 1.0f - 2.0f * fast_rcp(e + 1.0f); }

// Barrier that drains LDS ops only — global loads/stores stay in flight.
// (__syncthreads() emits s_waitcnt vmcnt(0) and serializes store/load
// latency into every step.)
__device__ __forceinline__ void sync_lds() {
    asm volatile("s_waitcnt lgkmcnt(0)" ::: "memory");
    __builtin_amdgcn_s_barrier();
    asm volatile("" ::: "memory");
}

// One-wave async global->LDS: 64 lanes x 4B = 256B (one full x row).
__device__ __forceinline__ void async_load_row(const float* gsrc, float* ldst) {
    __builtin_amdgcn_global_load_lds(
        (const __attribute__((address_space(1))) unsigned int*)gsrc,
        (__attribute__((address_space(3))) unsigned int*)ldst, 4, 0, 0);
}

// Scan kernel: one block per env, 768 threads = 12 waves.
//   tid [0,512):  gate threads. w[64] = W_hh row tid (f16 pairs). Full-row dot
//                 vs h (LDS broadcast) + pipelined xg; activation in-lane;
//                 write activated gate to g_lds[tid].
//   tid [512,768): xg threads (waves 8..11). 2 rows of W_ih each. Compute
//                 xg_{t+1} from x ring slot (t+1)&3; wave 8 issues the
//                 global_load_lds for x_{t+3} and does the counted vmcnt wait.
// Cell update by tid<128 between the two lgkm-only barriers. Raw h_t (f32)
// streamed to d_out; projection applied by kernel 2.
__global__ __launch_bounds__(768, 2)
void ppo_lstm_scan(const float* __restrict__ x,      // [T,B,D]
                   const float* __restrict__ done,   // [T,B]
                   const float* __restrict__ h0,     // [B,H]
                   const float* __restrict__ c0,     // [B,H]
                   const float* __restrict__ W_ih,   // [4H,D]
                   const float* __restrict__ b_ih,   // [4H]
                   const float* __restrict__ W_hh,   // [4H,H]
                   const float* __restrict__ b_hh,   // [4H]
                   float* __restrict__ hs)           // [T,B,H] = d_out (raw h)
{
    const int b    = blockIdx.x;
    const int tid  = threadIdx.x;
    const int lane = tid & 63;
    const int wid  = tid >> 6;

    __shared__ alignas(16) h2v   h_lds[H_DIM / 2];   // h_t f16 (256 B)
    __shared__ alignas(16) float g_lds[G4];          // activated gates (2 KB)
    __shared__ alignas(16) float xg_lds[2][G4];      // pipelined x-projection (4 KB)
    __shared__ alignas(16) float smask[T_STEPS];     // 1-done, preloaded (2 KB)
    __shared__ alignas(16) float xring[4][D_IN];     // x rows, 3-ahead ring (1 KB)

    h2v   w[64];
    float bias = 0.f, bias2 = 0.f, c_reg = 0.f;

    // ---- one-time: weight rows -> registers (f16) ----
    if (tid < G4) {
        const float* wr = W_hh + (size_t)tid * H_DIM;
        #pragma unroll
        for (int c = 0; c < 64; ++c) w[c] = pack16(wr[2 * c], wr[2 * c + 1]);
    } else {
        const int q = tid - G4;
        const float* wr0 = W_ih + (size_t)q * D_IN;
        const float* wr1 = W_ih + (size_t)(q + 256) * D_IN;
        #pragma unroll
        for (int c = 0; c < 32; ++c) w[c]      = pack16(wr0[2 * c], wr0[2 * c + 1]);
        #pragma unroll
        for (int c = 0; c < 32; ++c) w[32 + c] = pack16(wr1[2 * c], wr1[2 * c + 1]);
        bias  = b_ih[q]       + b_hh[q];
        bias2 = b_ih[q + 256] + b_hh[q + 256];
    }

    // ---- one-time: done mask, h0, c0, x ring prologue ----
    if (tid < T_STEPS) smask[tid] = 1.0f - done[(size_t)tid * B_ENV + b];
    if (tid < 64) {
        const float* hp = h0 + b * H_DIM;
        h_lds[tid] = pack16(hp[2 * tid], hp[2 * tid + 1]);
    }
    if (tid < H_DIM) c_reg = c0[b * H_DIM + tid];
    if (wid == 8) {
        #pragma unroll
        for (int s = 0; s < 3; ++s)
            async_load_row(x + ((size_t)s * B_ENV + b) * D_IN + lane, &xring[s][0]);
    }
    __syncthreads();   // full drain once: weights, smask, h0, x0..x2 all ready

    // xg_0 from x ring slot 0
    if (tid >= G4) {
        const int q = tid - G4;
        const f4v* xp = reinterpret_cast<const f4v*>(&xring[0][0]);
        float s0 = 0.f, s1 = 0.f;
        #pragma unroll
        for (int c4 = 0; c4 < 16; ++c4) {
            f4v xx = xp[c4];
            h2v xa = pack16(xx.x, xx.y), xb = pack16(xx.z, xx.w);
            s0 = dot2(w[2 * c4], xa, s0);      s0 = dot2(w[2 * c4 + 1], xb, s0);
            s1 = dot2(w[32 + 2 * c4], xa, s1); s1 = dot2(w[32 + 2 * c4 + 1], xb, s1);
        }
        xg_lds[0][q]       = s0 + bias;
        xg_lds[0][q + 256] = s1 + bias2;
    }
    sync_lds();

    for (int t = 0; t < T_STEPS; ++t) {
        const int   rbx = t & 1, wbx = rbx ^ 1;
        const float dm  = smask[t];

        if (tid < G4) {
            // gates for step t (h_lds holds hs[t-1]/h0)
            const h8v* hp8 = reinterpret_cast<const h8v*>(h_lds);
            float a0 = 0.f, a1 = 0.f, a2 = 0.f, a3 = 0.f;
            #pragma unroll
            for (int c = 0; c < 16; ++c) {
                union { h8v v; h2v p[4]; } u;
                u.v = hp8[c];
                a0 = dot2(w[4 * c + 0], u.p[0], a0);
                a1 = dot2(w[4 * c + 1], u.p[1], a1);
                a2 = dot2(w[4 * c + 2], u.p[2], a2);
                a3 = dot2(w[4 * c + 3], u.p[3], a3);
            }
            const float gs = xg_lds[rbx][tid] + dm * ((a0 + a1) + (a2 + a3));
            g_lds[tid] = ((tid >> 7) == 2) ? tanh_f(gs) : sigm(gs);
        } else {
            // x prefetch: wave 8 issues x_{t+3} (clamped; slot (t+3)&3)
            if (wid == 8) {
                const int t3 = (t + 3 < T_STEPS) ? (t + 3) : (T_STEPS - 1);
                async_load_row(x + ((size_t)t3 * B_ENV + b) * D_IN + lane,
                               &xring[(t + 3) & 3][0]);
            }
            // xg_{t+1} from ring slot (t+1)&3 (arrival proven last step)
            const int q = tid - G4;
            const f4v* xp = reinterpret_cast<const f4v*>(&xring[(t + 1) & 3][0]);
            float s0 = 0.f, s1 = 0.f;
            #pragma unroll
            for (int c4 = 0; c4 < 16; ++c4) {
                f4v xx = xp[c4];
                h2v xa = pack16(xx.x, xx.y), xb = pack16(xx.z, xx.w);
                s0 = dot2(w[2 * c4], xa, s0);      s0 = dot2(w[2 * c4 + 1], xb, s0);
                s1 = dot2(w[32 + 2 * c4], xa, s1); s1 = dot2(w[32 + 2 * c4 + 1], xb, s1);
            }
            xg_lds[wbx][q]       = s0 + bias;
            xg_lds[wbx][q + 256] = s1 + bias2;
        }
        sync_lds();   // barrier 1: gates + xg_{t+1} visible

        if (tid < H_DIM) {
            const float gi = g_lds[tid];
            const float gf = g_lds[H_DIM + tid];
            const float gg = g_lds[2 * H_DIM + tid];
            const float go = g_lds[3 * H_DIM + tid];
            const float cn = gf * (c_reg * dm) + gi * gg;
            c_reg = cn;
            const float hn = go * tanh_f(cn);
            reinterpret_cast<_Float16*>(h_lds)[tid] = (_Float16)hn;
            hs[((size_t)t * B_ENV + b) * H_DIM + tid] = hn;   // store stays in flight
        } else if (wid == 8) {
            // counted wait: of {x_{t+2}, x_{t+3}} outstanding, prove x_{t+2}
            // arrived before the barrier publishes the slot for step t+1.
            asm volatile("s_waitcnt vmcnt(1)" ::: "memory");
        }
        sync_lds();   // barrier 2: h_t visible
    }
}

// In-place row projection: out[r,:] = out_row @ W_hid^T + b_hid.
// 1024 blocks x 256 threads; block owns 128 rows (disjoint -> in-place safe).
#define PADK 68
__global__ __launch_bounds__(256)
void ppo_proj(const float* __restrict__ W_hid,   // [H,H]
              const float* __restrict__ b_hid,   // [H]
              float* __restrict__ out)           // [T*B, H] in-place
{
    __shared__ h2v wl[H_DIM][PADK];
    __shared__ h2v hl[H_DIM][PADK];
    const int tid = threadIdx.x;
    const int rg  = tid >> 4;    // 16 row-groups * 8 rows
    const int cg  = tid & 15;    // 16 col-groups, cols cg + 16*jj

    const size_t r0 = (size_t)blockIdx.x * H_DIM;

    #pragma unroll
    for (int i = 0; i < 16; ++i) {            // stage W_hid
        const int idx = tid + 256 * i;
        const int r = idx >> 5, cc = idx & 31;
        f4v v = *reinterpret_cast<const f4v*>(W_hid + 4 * (size_t)idx);
        wl[r][2 * cc]     = pack16(v.x, v.y);
        wl[r][2 * cc + 1] = pack16(v.z, v.w);
    }
    #pragma unroll
    for (int i = 0; i < 16; ++i) {            // stage 128 h rows
        const int idx = tid + 256 * i;
        const int r = idx >> 5, cc = idx & 31;
        f4v v = *reinterpret_cast<const f4v*>(out + (r0 + r) * H_DIM + 4 * cc);
        hl[r][2 * cc]     = pack16(v.x, v.y);
        hl[r][2 * cc + 1] = pack16(v.z, v.w);
    }
    float bcol[8];
    #pragma unroll
    for (int jj = 0; jj < 8; ++jj) bcol[jj] = b_hid[cg + 16 * jj];
    __syncthreads();

    float acc[8][8];
    #pragma unroll
    for (int i = 0; i < 8; ++i)
        #pragma unroll
        for (int jj = 0; jj < 8; ++jj) acc[i][jj] = 0.f;

    for (int kq = 0; kq < 16; ++kq) {
        union { h8v v; h2v p[4]; } hv[8], wv[8];
        #pragma unroll
        for (int i = 0; i < 8; ++i)
            hv[i].v = *reinterpret_cast<const h8v*>(&hl[rg * 8 + i][4 * kq]);
        #pragma unroll
        for (int jj = 0; jj < 8; ++jj)
            wv[jj].v = *reinterpret_cast<const h8v*>(&wl[cg + 16 * jj][4 * kq]);
        #pragma unroll
        for (int i = 0; i < 8; ++i)
            #pragma unroll
            for (int jj = 0; jj < 8; ++jj) {
                acc[i][jj] = dot2(hv[i].p[0], wv[jj].p[0], acc[i][jj]);
                acc[i][jj] = dot2(hv[i].p[1], wv[jj].p[1], acc[i][jj]);
                acc[i][jj] = dot2(hv[i].p[2], wv[jj].p[2], acc[i][jj]);
                acc[i][jj] = dot2(hv[i].p[3], wv[jj].p[3], acc[i][jj]);
            }
    }

    #pragma unroll
    for (int i = 0; i < 8; ++i)
        #pragma unroll
        for (int jj = 0; jj < 8; ++jj)
            out[(r0 + rg * 8 + i) * H_DIM + cg + 16 * jj] = acc[i][jj] + bcol[jj];
}

extern "C" void kernel_launch(void* const* d_in, const int* in_sizes, int n_in,
                              void* d_out, int out_size, void* d_ws, size_t ws_size,
                              hipStream_t stream) {
    const float* x     = (const float*)d_in[0];
    const float* done  = (const float*)d_in[1];
    const float* h0    = (const float*)d_in[2];
    const float* c0    = (const float*)d_in[3];
    const float* W_ih  = (const float*)d_in[4];
    const float* b_ih  = (const float*)d_in[5];
    const float* W_hh  = (const float*)d_in[6];
    const float* b_hh  = (const float*)d_in[7];
    const float* W_hid = (const float*)d_in[8];
    const float* b_hid = (const float*)d_in[9];
    float* out = (float*)d_out;
    (void)d_ws; (void)ws_size; (void)out_size; (void)n_in; (void)in_sizes;

    hipLaunchKernelGGL(ppo_lstm_scan, dim3(B_ENV), dim3(768), 0, stream,
                       x, done, h0, c0, W_ih, b_ih, W_hh, b_hh, out);
    hipLaunchKernelGGL(ppo_proj, dim3((T_STEPS * B_ENV) / H_DIM), dim3(256), 0, stream,
                       W_hid, b_hid, out);
}

// Round 7
// 530.022 us; speedup vs baseline: 4.5650x; 1.0461x over previous
//
#include <hip/hip_runtime.h>

#define T_STEPS 512
#define B_ENV   256
#define D_IN    64
#define H_DIM   128
#define G4      512   // 4*H gate rows

typedef _Float16 h2v __attribute__((ext_vector_type(2)));
typedef _Float16 h8v __attribute__((ext_vector_type(8)));
typedef float    f4v __attribute__((ext_vector_type(4)));

__device__ __forceinline__ float dot2(h2v a, h2v b, float c) {
#if __has_builtin(__builtin_amdgcn_fdot2)
    return __builtin_amdgcn_fdot2(a, b, c, false);
#else
    return c + (float)a.x * (float)b.x + (float)a.y * (float)b.y;
#endif
}

__device__ __forceinline__ h2v pack16(float a, float b) {
#if __has_builtin(__builtin_amdgcn_cvt_pkrtz)
    union { __fp16 __attribute__((ext_vector_type(2))) r; h2v h; } u;
    u.r = __builtin_amdgcn_cvt_pkrtz(a, b);
    return u.h;
#else
    h2v p; p.x = (_Float16)a; p.y = (_Float16)b; return p;
#endif
}

__device__ __forceinline__ float fast_rcp(float x) {
#if __has_builtin(__builtin_amdgcn_rcpf)
    return __builtin_amdgcn_rcpf(x);
#else
    return 1.0f / x;
#endif
}
__device__ __forceinline__ float sigm(float x)   { return fast_rcp(1.0f + __expf(-x)); }
__device__ __forceinline__ float tanh_f(float x) { float e = __expf(2.0f * x); return 1.0f - 2.0f * fast_rcp(e + 1.0f); }

// Quad reduction via DPP quad_perm — VALU pipe only (must NOT become
// ds_swizzle/ds_bpermute: the whole point is to unload the LDS pipe).
// 0xB1 = quad_perm(1,0,3,2) = xor1 ; 0x4E = quad_perm(2,3,0,1) = xor2.
template <int CTRL>
__device__ __forceinline__ float dpp_add(float v) {
    int s = __builtin_amdgcn_update_dpp(
        0, __builtin_bit_cast(int, v), CTRL, 0xF, 0xF, true);
    return v + __builtin_bit_cast(float, s);
}
__device__ __forceinline__ float quad_allreduce(float v) {
    v = dpp_add<0xB1>(v);
    v = dpp_add<0x4E>(v);
    return v;
}

// Barrier that drains LDS ops only — global loads/stores stay in flight.
__device__ __forceinline__ void sync_lds() {
    asm volatile("s_waitcnt lgkmcnt(0)" ::: "memory");
    __builtin_amdgcn_s_barrier();
    asm volatile("" ::: "memory");
}

// One-wave async global->LDS: 64 lanes x 4B = 256B (one full x row).
__device__ __forceinline__ void async_load_row(const float* gsrc, float* ldst) {
    __builtin_amdgcn_global_load_lds(
        (const __attribute__((address_space(1))) unsigned int*)gsrc,
        (__attribute__((address_space(3))) unsigned int*)ldst, 4, 0, 0);
}

// Scan: one block per env, 768 threads = 12 waves, ONE lgkm barrier/step.
//  tid [0,512):  gate quads. j=tid>>2, qq=tid&3. Thread holds k-quarter qq of
//                W_hh rows {j,128+j,256+j,384+j} (64 h2v). Partial dots ->
//                DPP quad allreduce -> activations + cell update in-lane
//                (c replicated in quad) -> qq==0 writes h (f16) + hs (f32).
//  tid [512,768): xg quads. q2=(tid-512)>>2. Thread holds x-quarter qq of
//                W_ih rows {g*128+2q2+rr} (64 h2v). Computes xg_{t+1} from
//                x ring slot; lanes qq<2 write f4v to xg_lds[wb][2q2+qq][4].
//                Wave 8 issues global_load_lds x_{t+3} + counted vmcnt(1).
__global__ __launch_bounds__(768, 2)
void ppo_lstm_scan(const float* __restrict__ x,      // [T,B,D]
                   const float* __restrict__ done,   // [T,B]
                   const float* __restrict__ h0,     // [B,H]
                   const float* __restrict__ c0,     // [B,H]
                   const float* __restrict__ W_ih,   // [4H,D]
                   const float* __restrict__ b_ih,   // [4H]
                   const float* __restrict__ W_hh,   // [4H,H]
                   const float* __restrict__ b_hh,   // [4H]
                   float* __restrict__ hs)           // [T,B,H] = d_out (raw h)
{
    const int b    = blockIdx.x;
    const int tid  = threadIdx.x;
    const int lane = tid & 63;
    const int wid  = tid >> 6;
    const int qq   = tid & 3;

    __shared__ alignas(16) h2v   h_lds[2][H_DIM / 2];   // h f16, dbuf (512 B)
    __shared__ alignas(16) float xg_lds[2][H_DIM][4];   // xg [j][gate], dbuf (4 KB)
    __shared__ alignas(16) float smask[T_STEPS];        // 1-done (2 KB)
    __shared__ alignas(16) float xring[4][D_IN];        // x rows, ring (1 KB)

    h2v  w[64];
    f4v  bias4 = {0.f, 0.f, 0.f, 0.f};
    float c_reg = 0.f;

    const int j  = tid >> 2;          // gate threads: h index
    const int q2 = (tid - G4) >> 2;   // xg threads: quad id

    // ---- one-time: weight slices -> registers (f16) ----
    if (tid < G4) {
        #pragma unroll
        for (int g = 0; g < 4; ++g) {
            const float* wr = W_hh + (size_t)(g * H_DIM + j) * H_DIM + qq * 32;
            #pragma unroll
            for (int c = 0; c < 16; ++c)
                w[g * 16 + c] = pack16(wr[2 * c], wr[2 * c + 1]);
        }
        c_reg = c0[b * H_DIM + j];
    } else {
        const int rr = qq & 1;        // bias row parity this lane will write
        #pragma unroll
        for (int rr2 = 0; rr2 < 2; ++rr2)
            #pragma unroll
            for (int g = 0; g < 4; ++g) {
                const int r = g * H_DIM + 2 * q2 + rr2;
                const float* wr = W_ih + (size_t)r * D_IN + qq * 16;
                #pragma unroll
                for (int c = 0; c < 8; ++c)
                    w[(rr2 * 4 + g) * 8 + c] = pack16(wr[2 * c], wr[2 * c + 1]);
            }
        #pragma unroll
        for (int g = 0; g < 4; ++g) {
            const int r = g * H_DIM + 2 * q2 + rr;
            bias4[g] = b_ih[r] + b_hh[r];
        }
    }

    // ---- one-time: done mask, h0, x ring prologue ----
    if (tid < T_STEPS) smask[tid] = 1.0f - done[(size_t)tid * B_ENV + b];
    if (tid < 64) {
        const float* hp = h0 + b * H_DIM;
        h_lds[0][tid] = pack16(hp[2 * tid], hp[2 * tid + 1]);
    }
    if (wid == 8) {
        #pragma unroll
        for (int s = 0; s < 3; ++s)
            async_load_row(x + ((size_t)s * B_ENV + b) * D_IN + lane, &xring[s][0]);
    }
    __syncthreads();   // full drain once: weights visible, x0..x2 landed

    // xg compute: slot -> xg_lds[buf]
    auto xg_compute = [&](int slot, int buf) {
        const f4v* xp = reinterpret_cast<const f4v*>(&xring[slot][qq * 16]);
        h2v xh[8];
        #pragma unroll
        for (int c4 = 0; c4 < 4; ++c4) {
            f4v xx = xp[c4];
            xh[2 * c4]     = pack16(xx.x, xx.y);
            xh[2 * c4 + 1] = pack16(xx.z, xx.w);
        }
        float ps[8];
        #pragma unroll
        for (int i = 0; i < 8; ++i) ps[i] = 0.f;
        #pragma unroll
        for (int i = 0; i < 8; ++i)
            #pragma unroll
            for (int c = 0; c < 8; ++c)
                ps[i] = dot2(w[i * 8 + c], xh[c], ps[i]);
        #pragma unroll
        for (int i = 0; i < 8; ++i) ps[i] = quad_allreduce(ps[i]);
        if (qq < 2) {
            f4v o;
            #pragma unroll
            for (int g = 0; g < 4; ++g) o[g] = ps[qq * 4 + g] + bias4[g];
            *reinterpret_cast<f4v*>(&xg_lds[buf][2 * q2 + qq][0]) = o;
        }
    };

    if (tid >= G4) xg_compute(0, 0);
    sync_lds();

    for (int t = 0; t < T_STEPS; ++t) {
        const int rb = t & 1, wb = rb ^ 1;

        if (tid < G4) {
            const float dm = smask[t];
            // k-quarter partial dots for 4 gate rows of j
            const h8v* hp8 = reinterpret_cast<const h8v*>(&h_lds[rb][0]);
            float p0 = 0.f, p1 = 0.f, p2 = 0.f, p3 = 0.f;
            #pragma unroll
            for (int c4 = 0; c4 < 4; ++c4) {
                union { h8v v; h2v p[4]; } u;
                u.v = hp8[qq * 4 + c4];
                #pragma unroll
                for (int pp = 0; pp < 4; ++pp) {
                    p0 = dot2(w[      c4 * 4 + pp], u.p[pp], p0);
                    p1 = dot2(w[16 +  c4 * 4 + pp], u.p[pp], p1);
                    p2 = dot2(w[32 +  c4 * 4 + pp], u.p[pp], p2);
                    p3 = dot2(w[48 +  c4 * 4 + pp], u.p[pp], p3);
                }
            }
            p0 = quad_allreduce(p0);
            p1 = quad_allreduce(p1);
            p2 = quad_allreduce(p2);
            p3 = quad_allreduce(p3);
            const f4v xg4 = *reinterpret_cast<const f4v*>(&xg_lds[rb][j][0]);
            const float gi = xg4.x + dm * p0;
            const float gf = xg4.y + dm * p1;
            const float gg = xg4.z + dm * p2;
            const float go = xg4.w + dm * p3;
            const float cn = sigm(gf) * (c_reg * dm) + sigm(gi) * tanh_f(gg);
            c_reg = cn;                     // replicated, bit-identical in quad
            const float hn = sigm(go) * tanh_f(cn);
            if (qq == 0) {
                reinterpret_cast<_Float16*>(h_lds[wb])[j] = (_Float16)hn;
                hs[((size_t)t * B_ENV + b) * H_DIM + j] = hn;  // stays in flight
            }
        } else {
            if (wid == 8) {
                const int t3 = (t + 3 < T_STEPS) ? (t + 3) : (T_STEPS - 1);
                async_load_row(x + ((size_t)t3 * B_ENV + b) * D_IN + lane,
                               &xring[(t + 3) & 3][0]);
            }
            xg_compute((t + 1) & 3, wb);    // harmless garbage at t=511
            if (wid == 8) {
                // prove x_{t+2} landed before the barrier publishes it
                asm volatile("s_waitcnt vmcnt(1)" ::: "memory");
            }
        }
        sync_lds();   // single barrier: h_t, xg_{t+1}, x_{t+2} all published
    }
}

// In-place row projection: out[r,:] = out_row @ W_hid^T + b_hid.
// 1024 blocks x 256 threads; block owns 128 rows (disjoint -> in-place safe).
#define PADK 68
__global__ __launch_bounds__(256)
void ppo_proj(const float* __restrict__ W_hid,   // [H,H]
              const float* __restrict__ b_hid,   // [H]
              float* __restrict__ out)           // [T*B, H] in-place
{
    __shared__ h2v wl[H_DIM][PADK];
    __shared__ h2v hl[H_DIM][PADK];
    const int tid = threadIdx.x;
    const int rg  = tid >> 4;
    const int cg  = tid & 15;

    const size_t r0 = (size_t)blockIdx.x * H_DIM;

    #pragma unroll
    for (int i = 0; i < 16; ++i) {
        const int idx = tid + 256 * i;
        const int r = idx >> 5, cc = idx & 31;
        f4v v = *reinterpret_cast<const f4v*>(W_hid + 4 * (size_t)idx);
        wl[r][2 * cc]     = pack16(v.x, v.y);
        wl[r][2 * cc + 1] = pack16(v.z, v.w);
    }
    #pragma unroll
    for (int i = 0; i < 16; ++i) {
        const int idx = tid + 256 * i;
        const int r = idx >> 5, cc = idx & 31;
        f4v v = *reinterpret_cast<const f4v*>(out + (r0 + r) * H_DIM + 4 * cc);
        hl[r][2 * cc]     = pack16(v.x, v.y);
        hl[r][2 * cc + 1] = pack16(v.z, v.w);
    }
    float bcol[8];
    #pragma unroll
    for (int jj = 0; jj < 8; ++jj) bcol[jj] = b_hid[cg + 16 * jj];
    __syncthreads();

    float acc[8][8];
    #pragma unroll
    for (int i = 0; i < 8; ++i)
        #pragma unroll
        for (int jj = 0; jj < 8; ++jj) acc[i][jj] = 0.f;

    for (int kq = 0; kq < 16; ++kq) {
        union { h8v v; h2v p[4]; } hv[8], wv[8];
        #pragma unroll
        for (int i = 0; i < 8; ++i)
            hv[i].v = *reinterpret_cast<const h8v*>(&hl[rg * 8 + i][4 * kq]);
        #pragma unroll
        for (int jj = 0; jj < 8; ++jj)
            wv[jj].v = *reinterpret_cast<const h8v*>(&wl[cg + 16 * jj][4 * kq]);
        #pragma unroll
        for (int i = 0; i < 8; ++i)
            #pragma unroll
            for (int jj = 0; jj < 8; ++jj) {
                acc[i][jj] = dot2(hv[i].p[0], wv[jj].p[0], acc[i][jj]);
                acc[i][jj] = dot2(hv[i].p[1], wv[jj].p[1], acc[i][jj]);
                acc[i][jj] = dot2(hv[i].p[2], wv[jj].p[2], acc[i][jj]);
                acc[i][jj] = dot2(hv[i].p[3], wv[jj].p[3], acc[i][jj]);
            }
    }

    #pragma unroll
    for (int i = 0; i < 8; ++i)
        #pragma unroll
        for (int jj = 0; jj < 8; ++jj)
            out[(r0 + rg * 8 + i) * H_DIM + cg + 16 * jj] = acc[i][jj] + bcol[jj];
}

extern "C" void kernel_launch(void* const* d_in, const int* in_sizes, int n_in,
                              void* d_out, int out_size, void* d_ws, size_t ws_size,
                              hipStream_t stream) {
    const float* x     = (const float*)d_in[0];
    const float* done  = (const float*)d_in[1];
    const float* h0    = (const float*)d_in[2];
    const float* c0    = (const float*)d_in[3];
    const float* W_ih  = (const float*)d_in[4];
    const float* b_ih  = (const float*)d_in[5];
    const float* W_hh  = (const float*)d_in[6];
    const float* b_hh  = (const float*)d_in[7];
    const float* W_hid = (const float*)d_in[8];
    const float* b_hid = (const float*)d_in[9];
    float* out = (float*)d_out;
    (void)d_ws; (void)ws_size; (void)out_size; (void)n_in; (void)in_sizes;

    hipLaunchKernelGGL(ppo_lstm_scan, dim3(B_ENV), dim3(768), 0, stream,
                       x, done, h0, c0, W_ih, b_ih, W_hh, b_hh, out);
    hipLaunchKernelGGL(ppo_proj, dim3((T_STEPS * B_ENV) / H_DIM), dim3(256), 0, stream,
                       W_hid, b_hid, out);
}

// Round 8
// 511.419 us; speedup vs baseline: 4.7311x; 1.0364x over previous
//
#include <hip/hip_runtime.h>

#define T_STEPS 512
#define B_ENV   256
#define D_IN    64
#define H_DIM   128
#define G4      512   // 4*H gate rows

typedef _Float16 h2v __attribute__((ext_vector_type(2)));
typedef _Float16 h8v __attribute__((ext_vector_type(8)));
typedef float    f4v __attribute__((ext_vector_type(4)));

__device__ __forceinline__ float dot2(h2v a, h2v b, float c) {
#if __has_builtin(__builtin_amdgcn_fdot2)
    return __builtin_amdgcn_fdot2(a, b, c, false);
#else
    return c + (float)a.x * (float)b.x + (float)a.y * (float)b.y;
#endif
}

__device__ __forceinline__ h2v pack16(float a, float b) {
#if __has_builtin(__builtin_amdgcn_cvt_pkrtz)
    union { __fp16 __attribute__((ext_vector_type(2))) r; h2v h; } u;
    u.r = __builtin_amdgcn_cvt_pkrtz(a, b);
    return u.h;
#else
    h2v p; p.x = (_Float16)a; p.y = (_Float16)b; return p;
#endif
}

__device__ __forceinline__ float fast_rcp(float x) {
#if __has_builtin(__builtin_amdgcn_rcpf)
    return __builtin_amdgcn_rcpf(x);
#else
    return 1.0f / x;
#endif
}
__device__ __forceinline__ float sigm(float x)   { return fast_rcp(1.0f + __expf(-x)); }
__device__ __forceinline__ float tanh_f(float x) { float e = __expf(2.0f * x); return 1.0f - 2.0f * fast_rcp(e + 1.0f); }

// Quad-lane broadcast via DPP quad_perm (VALU pipe, no LDS).
// ctrl = p|p<<2|p<<4|p<<6 broadcasts quad lane p to all 4 lanes.
template <int CTRL>
__device__ __forceinline__ float dpp_bcast(float v) {
    int s = __builtin_amdgcn_update_dpp(
        0, __builtin_bit_cast(int, v), CTRL, 0xF, 0xF, true);
    return __builtin_bit_cast(float, s);
}

// Barrier draining LDS ops only — global loads/stores stay in flight.
__device__ __forceinline__ void sync_lds() {
    asm volatile("s_waitcnt lgkmcnt(0)" ::: "memory");
    __builtin_amdgcn_s_barrier();
    asm volatile("" ::: "memory");
}

// One-wave async global->LDS: 64 lanes x 4B = 256B (one full x row).
__device__ __forceinline__ void async_load_row(const float* gsrc, float* ldst) {
    __builtin_amdgcn_global_lo\
ad_lds(
        (const __attribute__((address_space(1))) unsigned int*)gsrc,
        (__attribute__((address_space(3))) unsigned int*)ldst, 4, 0, 0);
}

// Scan: one block per env, 512 threads = 8 waves, ONE lgkm barrier/step.
// Thread (j = tid>>2, g = tid&3) owns the FULL row r = g*128+j of W_hh
// (64 h2v) and W_ih (32 h2v) in registers. Per step:
//   full-row dots vs h (16 uniform b128) and x-f16 (8 uniform b128)
//   -> one activation (own gate; lane-specialized: g==2 tanh else sigm)
//   -> 4x DPP quad-broadcast to share activated i,f,g,o
//   -> cell update replicated in quad (bit-identical) -> g==0 writes
//      h (f16, dbuf) + raw h to d_out (store stays in flight).
// Wave 0 additionally: issues x_{t+3} global_load_lds into a 4-slot f32
// ring, converts x_{t+1} f32->f16 (32 lanes, 3 LDS ops), and does the
// counted s_waitcnt vmcnt(1) BEFORE its own hs store so stores don't
// pollute the count.
__global__ __launch_bounds__(512, 2)
void ppo_lstm_scan(const float* __restrict__ x,      // [T,B,D]
                   const float* __restrict__ done,   // [T,B]
                   const float* __restrict__ h0,     // [B,H]
                   const float* __restrict__ c0,     // [B,H]
                   const float* __restrict__ W_ih,   // [4H,D]
                   const float* __restrict__ b_ih,   // [4H]
                   const float* __restrict__ W_hh,   // [4H,H]
                   const float* __restrict__ b_hh,   // [4H]
                   float* __restrict__ hs)           // [T,B,H] = d_out (raw h)
{
    const int b    = blockIdx.x;
    const int tid  = threadIdx.x;
    const int lane = tid & 63;
    const int wid  = tid >> 6;
    const int g    = tid & 3;
    const int j    = tid >> 2;
    const int r    = g * H_DIM + j;   // owned gate row

    __shared__ alignas(16) h2v   h16[2][H_DIM / 2];  // h f16, dbuf (512 B)
    __shared__ alignas(16) h2v   x16[2][D_IN / 2];   // x f16, dbuf (256 B)
    __shared__ alignas(16) float smask[T_STEPS];     // 1-done (2 KB)
    __shared__ alignas(16) float xring[4][D_IN];     // x f32 ring (1 KB)

    // ---- one-time: full weight rows -> registers (f16) ----
    h2v whh[64];
    h2v wih[32];
    {
        const float* wr = W_hh + (size_t)r * H_DIM;
        #pragma unroll
        for (int c = 0; c < 64; ++c) whh[c] = pack16(wr[2 * c], wr[2 * c + 1]);
        const float* wr2 = W_ih + (size_t)r * D_IN;
        #pragma unroll
        for (int c = 0; c < 32; ++c) wih[c] = pack16(wr2[2 * c], wr2[2 * c + 1]);
    }
    const float bias  = b_ih[r] + b_hh[r];
    float       c_reg = c0[b * H_DIM + j];

    // ---- one-time: done mask, h0, x ring prologue ----
    smask[tid] = 1.0f - done[(size_t)tid * B_ENV + b];   // tid == t (512 == T)
    if (tid < 64) {
        const float* hp = h0 + b * H_DIM;
        h16[0][tid] = pack16(hp[2 * tid], hp[2 * tid + 1]);
    }
    if (wid == 0) {
        #pragma unroll
        for (int s = 0; s < 3; ++s)
            async_load_row(x + ((size_t)s * B_ENV + b) * D_IN + lane, &xring[s][0]);
    }
    __syncthreads();                 // full drain once: x0..x2 landed, LDS ready
    if (wid == 0 && lane < 32) {     // convert x0 -> x16[0]
        float2 v = *reinterpret_cast<const float2*>(&xring[0][2 * lane]);
        x16[0][lane] = pack16(v.x, v.y);
    }
    sync_lds();

    for (int t = 0; t < T_STEPS; ++t) {
        const int rb = t & 1, wb = rb ^ 1;

        if (wid == 0) {
            // issue x_{t+3} (slot free: last read at step t-1)
            const int t3 = (t + 3 < T_STEPS) ? (t + 3) : (T_STEPS - 1);
            async_load_row(x + ((size_t)t3 * B_ENV + b) * D_IN + lane,
                           &xring[(t + 3) & 3][0]);
            // convert x_{t+1} (arrival proven by last step's vmcnt wait)
            if (lane < 32) {
                float2 v = *reinterpret_cast<const float2*>(
                    &xring[(t + 1) & 3][2 * lane]);
                x16[wb][lane] = pack16(v.x, v.y);
            }
        }
        const float dm = smask[t];

        // full-row dots: h (64 h2v) + x (32 h2v), uniform broadcast reads
        const h8v* hp = reinterpret_cast<const h8v*>(&h16[rb][0]);
        const h8v* xp = reinterpret_cast<const h8v*>(&x16[rb][0]);
        float a0 = 0.f, a1 = 0.f, a2 = 0.f, a3 = 0.f;
        #pragma unroll
        for (int c = 0; c < 16; ++c) {
            union { h8v v; h2v p[4]; } u;
            u.v = hp[c];
            a0 = dot2(whh[4 * c + 0], u.p[0], a0);
            a1 = dot2(whh[4 * c + 1], u.p[1], a1);
            a2 = dot2(whh[4 * c + 2], u.p[2], a2);
            a3 = dot2(whh[4 * c + 3], u.p[3], a3);
        }
        float b0 = bias, b1 = 0.f;
        #pragma unroll
        for (int c = 0; c < 8; ++c) {
            union { h8v v; h2v p[4]; } u;
            u.v = xp[c];
            b0 = dot2(wih[4 * c + 0], u.p[0], b0);
            b1 = dot2(wih[4 * c + 1], u.p[1], b1);
            b0 = dot2(wih[4 * c + 2], u.p[2], b0);
            b1 = dot2(wih[4 * c + 3], u.p[3], b1);
        }
        const float gs = (b0 + b1) + dm * ((a0 + a1) + (a2 + a3));

        // ONE activation per thread (own gate), then quad-broadcast
        const float av = (g == 2) ? tanh_f(gs) : sigm(gs);
        const float ai = dpp_bcast<0x00>(av);
        const float af = dpp_bcast<0x55>(av);
        const float ag = dpp_bcast<0xAA>(av);
        const float ao = dpp_bcast<0xFF>(av);

        // cell update, replicated (bit-identical) in quad
        const float cn = af * (c_reg * dm) + ai * ag;
        c_reg = cn;
        const float hn = ao * tanh_f(cn);

        if (wid == 0) {
            // counted wait BEFORE this wave's store: outstanding = {x_{t+3}}
            // (+ maybe an old retired-soon store) -> proves x_{t+2} landed.
            asm volatile("s_waitcnt vmcnt(1)" ::: "memory");
        }
        if (g == 0) {
            reinterpret_cast<_Float16*>(h16[wb])[j] = (_Float16)hn;
            hs[((size_t)t * B_ENV + b) * H_DIM + j] = hn;   // stays in flight
        }
        sync_lds();   // single barrier: h_t, x16_{t+1}, x_{t+2} all published
    }
}

// In-place row projection: out[r,:] = out_row @ W_hid^T + b_hid.
// 1024 blocks x 256 threads; block owns 128 rows (disjoint -> in-place safe).
#define PADK 68
__global__ __launch_bounds__(256)
void ppo_proj(const float* __restrict__ W_hid,   // [H,H]
              const float* __restrict__ b_hid,   // [H]
              float* __restrict__ out)           // [T*B, H] in-place
{
    __shared__ h2v wl[H_DIM][PADK];
    __shared__ h2v hl[H_DIM][PADK];
    const int tid = threadIdx.x;
    const int rg  = tid >> 4;
    const int cg  = tid & 15;

    const size_t r0 = (size_t)blockIdx.x * H_DIM;

    #pragma unroll
    for (int i = 0; i < 16; ++i) {
        const int idx = tid + 256 * i;
        const int r = idx >> 5, cc = idx & 31;
        f4v v = *reinterpret_cast<const f4v*>(W_hid + 4 * (size_t)idx);
        wl[r][2 * cc]     = pack16(v.x, v.y);
        wl[r][2 * cc + 1] = pack16(v.z, v.w);
    }
    #pragma unroll
    for (int i = 0; i < 16; ++i) {
        const int idx = tid + 256 * i;
        const int r = idx >> 5, cc = idx & 31;
        f4v v = *reinterpret_cast<const f4v*>(out + (r0 + r) * H_DIM + 4 * cc);
        hl[r][2 * cc]     = pack16(v.x, v.y);
        hl[r][2 * cc + 1] = pack16(v.z, v.w);
    }
    float bcol[8];
    #pragma unroll
    for (int jj = 0; jj < 8; ++jj) bcol[jj] = b_hid[cg + 16 * jj];
    __syncthreads();

    float acc[8][8];
    #pragma unroll
    for (int i = 0; i < 8; ++i)
        #pragma unroll
        for (int jj = 0; jj < 8; ++jj) acc[i][jj] = 0.f;

    for (int kq = 0; kq < 16; ++kq) {
        union { h8v v; h2v p[4]; } hv[8], wv[8];
        #pragma unroll
        for (int i = 0; i < 8; ++i)
            hv[i].v = *reinterpret_cast<const h8v*>(&hl[rg * 8 + i][4 * kq]);
        #pragma unroll
        for (int jj = 0; jj < 8; ++jj)
            wv[jj].v = *reinterpret_cast<const h8v*>(&wl[cg + 16 * jj][4 * kq]);
        #pragma unroll
        for (int i = 0; i < 8; ++i)
            #pragma unroll
            for (int jj = 0; jj < 8; ++jj) {
                acc[i][jj] = dot2(hv[i].p[0], wv[jj].p[0], acc[i][jj]);
                acc[i][jj] = dot2(hv[i].p[1], wv[jj].p[1], acc[i][jj]);
                acc[i][jj] = dot2(hv[i].p[2], wv[jj].p[2], acc[i][jj]);
                acc[i][jj] = dot2(hv[i].p[3], wv[jj].p[3], acc[i][jj]);
            }
    }

    #pragma unroll
    for (int i = 0; i < 8; ++i)
        #pragma unroll
        for (int jj = 0; jj < 8; ++jj)
            out[(r0 + rg * 8 + i) * H_DIM + cg + 16 * jj] = acc[i][jj] + bcol[jj];
}

extern "C" void kernel_launch(void* const* d_in, const int* in_sizes, int n_in,
                              void* d_out, int out_size, void* d_ws, size_t ws_size,
                              hipStream_t stream) {
    const float* x     = (const float*)d_in[0];
    const float* done  = (const float*)d_in[1];
    const float* h0    = (const float*)d_in[2];
    const float* c0    = (const float*)d_in[3];
    const float* W_ih  = (const float*)d_in[4];
    const float* b_ih  = (const float*)d_in[5];
    const float* W_hh  = (const float*)d_in[6];
    const float* b_hh  = (const float*)d_in[7];
    const float* W_hid = (const float*)d_in[8];
    const float* b_hid = (const float*)d_in[9];
    float* out = (float*)d_out;
    (void)d_ws; (void)ws_size; (void)out_size; (void)n_in; (void)in_sizes;

    hipLaunchKernelGGL(ppo_lstm_scan, dim3(B_ENV), dim3(512), 0, stream,
                       x, done, h0, c0, W_ih, b_ih, W_hh, b_hh, out);
    hipLaunchKernelGGL(ppo_proj, dim3((T_STEPS * B_ENV) / H_DIM), dim3(256), 0, stream,
                       W_hid, b_hid, out);
}

// Round 9
// 445.632 us; speedup vs baseline: 5.4295x; 1.1476x over previous
//
#include <hip/hip_runtime.h>

#define T_STEPS 512
#define B_ENV   256
#define D_IN    64
#define H_DIM   128
#define G4      512   // 4*H gate rows

typedef _Float16 h2v __attribute__((ext_vector_type(2)));
typedef _Float16 h8v __attribute__((ext_vector_type(8)));
typedef float    f4v __attribute__((ext_vector_type(4)));

__device__ __forceinline__ float dot2(h2v a, h2v b, float c) {
#if __has_builtin(__builtin_amdgcn_fdot2)
    return __builtin_amdgcn_fdot2(a, b, c, false);
#else
    return c + (float)a.x * (float)b.x + (float)a.y * (float)b.y;
#endif
}

__device__ __forceinline__ h2v pack16(float a, float b) {
#if __has_builtin(__builtin_amdgcn_cvt_pkrtz)
    union { __fp16 __attribute__((ext_vector_type(2))) r; h2v h; } u;
    u.r = __builtin_amdgcn_cvt_pkrtz(a, b);
    return u.h;
#else
    h2v p; p.x = (_Float16)a; p.y = (_Float16)b; return p;
#endif
}

__device__ __forceinline__ float fast_rcp(float x) {
#if __has_builtin(__builtin_amdgcn_rcpf)
    return __builtin_amdgcn_rcpf(x);
#else
    return 1.0f / x;
#endif
}
__device__ __forceinline__ float sigm(float x)   { return fast_rcp(1.0f + __expf(-x)); }
__device__ __forceinline__ float tanh_f(float x) { float e = __expf(2.0f * x); return 1.0f - 2.0f * fast_rcp(e + 1.0f); }

// DPP quad_perm ops (VALU pipe — never LDS).
template <int CTRL>
__device__ __forceinline__ float dpp_mov(float v) {
    int s = __builtin_amdgcn_update_dpp(
        0, __builtin_bit_cast(int, v), CTRL, 0xF, 0xF, true);
    return __builtin_bit_cast(float, s);
}
__device__ __forceinline__ float quad_allreduce(float v) {
    v += dpp_mov<0xB1>(v);   // quad_perm(1,0,3,2): xor1
    v += dpp_mov<0x4E>(v);   // quad_perm(2,3,0,1): xor2
    return v;
}

// Barrier draining LDS ops only — global loads/stores stay in flight.
__device__ __forceinline__ void sync_lds() {
    asm volatile("s_waitcnt lgkmcnt(0)" ::: "memory");
    __builtin_amdgcn_s_barrier();
    asm volatile("" ::: "memory");
}

// One-wave async global->LDS: 64 lanes x 4B = 256B (one full x row).
__device__ __forceinline__ void async_load_row(const float* gsrc, float* ldst) {
    __builtin_amdgcn_global_load_lds(
        (const __attribute__((address_space(1))) unsigned int*)gsrc,
        (__attribute__((address_space(3))) unsigned int*)ldst, 4, 0, 0);
}

// Scan: one block per env, 512 threads = 8 waves, ONE lgkm barrier/step.
// Thread (j = tid>>2, qq = tid&3) owns k-quarter qq of the 4 gate rows
// {j, 128+j, 256+j, 384+j}: W_hh[4][16] + W_ih[4][8] h2v in registers.
// Per step: 4 ds_read_b128 (h quarter, per-lane distinct -> whole wave
// reads 256B in 4 instrs) + 2 (x quarter) -> 96 dot2 into 4 gate accs
// -> DPP quad allreduce -> lane qq activates gate qq only -> DPP quad
// broadcast -> replicated cell update -> qq==0 writes h16 (PRE-SCALED by
// smask[t+1], so the dot path needs no mask) + raw h to d_out.
// Wave 0 drives the x ring: global_load_lds x_{t+3}, f32->f16 convert of
// x_{t+1}, counted s_waitcnt vmcnt(1) before its store.
__global__ __launch_bounds__(512, 2)
void ppo_lstm_scan(const float* __restrict__ x,      // [T,B,D]
                   const float* __restrict__ done,   // [T,B]
                   const float* __restrict__ h0,     // [B,H]
                   const float* __restrict__ c0,     // [B,H]
                   const float* __restrict__ W_ih,   // [4H,D]
                   const float* __restrict__ b_ih,   // [4H]
                   const float* __restrict__ W_hh,   // [4H,H]
                   const float* __restrict__ b_hh,   // [4H]
                   float* __restrict__ hs)           // [T,B,H] = d_out (raw h)
{
    const int b    = blockIdx.x;
    const int tid  = threadIdx.x;
    const int lane = tid & 63;
    const int wid  = tid >> 6;
    const int qq   = tid & 3;
    const int j    = tid >> 2;

    __shared__ alignas(16) h2v   h16[2][H_DIM / 2];  // h f16 (pre-masked), dbuf
    __shared__ alignas(16) h2v   x16[2][D_IN / 2];   // x f16, dbuf
    __shared__ alignas(16) float smask[T_STEPS];     // 1-done
    __shared__ alignas(16) float xring[4][D_IN];     // x f32 ring

    // ---- one-time: weight slices -> registers (f16) ----
    h2v whh[64];   // gate g, k-quarter qq: 16 h2v each
    h2v wih[32];   // gate g, x-quarter qq: 8 h2v each
    #pragma unroll
    for (int g = 0; g < 4; ++g) {
        const float* wr = W_hh + (size_t)(g * H_DIM + j) * H_DIM + qq * 32;
        #pragma unroll
        for (int c = 0; c < 16; ++c)
            whh[g * 16 + c] = pack16(wr[2 * c], wr[2 * c + 1]);
        const float* wr2 = W_ih + (size_t)(g * H_DIM + j) * D_IN + qq * 16;
        #pragma unroll
        for (int c = 0; c < 8; ++c)
            wih[g * 8 + c] = pack16(wr2[2 * c], wr2[2 * c + 1]);
    }
    const int   r_own    = qq * H_DIM + j;
    const float bias_own = b_ih[r_own] + b_hh[r_own];
    float       c_reg    = c0[b * H_DIM + j];

    // ---- one-time: done mask, h0 (pre-scaled), x ring prologue ----
    smask[tid] = 1.0f - done[(size_t)tid * B_ENV + b];   // tid == t
    if (tid < 64) {
        const float sm0 = 1.0f - done[b];
        const float* hp = h0 + b * H_DIM;
        h16[0][tid] = pack16(hp[2 * tid] * sm0, hp[2 * tid + 1] * sm0);
    }
    if (wid == 0) {
        #pragma unroll
        for (int s = 0; s < 3; ++s)
            async_load_row(x + ((size_t)s * B_ENV + b) * D_IN + lane, &xring[s][0]);
    }
    __syncthreads();                 // full drain once: x0..x2 landed
    if (wid == 0 && lane < 32) {     // convert x0 -> x16[0]
        float2 v = *reinterpret_cast<const float2*>(&xring[0][2 * lane]);
        x16[0][lane] = pack16(v.x, v.y);
    }
    sync_lds();

    for (int t = 0; t < T_STEPS; ++t) {
        const int rb = t & 1, wb = rb ^ 1;

        if (wid == 0) {
            const int t3 = (t + 3 < T_STEPS) ? (t + 3) : (T_STEPS - 1);
            async_load_row(x + ((size_t)t3 * B_ENV + b) * D_IN + lane,
                           &xring[(t + 3) & 3][0]);
            if (lane < 32) {   // convert x_{t+1} (landed: last step's vmcnt)
                float2 v = *reinterpret_cast<const float2*>(
                    &xring[(t + 1) & 3][2 * lane]);
                x16[wb][lane] = pack16(v.x, v.y);
            }
        }

        // ---- k-quarter dots: 4 b128 (h) + 2 b128 (x), per-lane distinct ----
        const h8v* hp8 = reinterpret_cast<const h8v*>(&h16[rb][qq * 16]);
        const h8v* xp8 = reinterpret_cast<const h8v*>(&x16[rb][qq * 8]);
        float s0 = 0.f, s1 = 0.f, s2 = 0.f, s3 = 0.f;
        #pragma unroll
        for (int c4 = 0; c4 < 4; ++c4) {
            union { h8v v; h2v p[4]; } u;
            u.v = hp8[c4];
            #pragma unroll
            for (int pp = 0; pp < 4; ++pp) {
                s0 = dot2(whh[      c4 * 4 + pp], u.p[pp], s0);
                s1 = dot2(whh[16 +  c4 * 4 + pp], u.p[pp], s1);
                s2 = dot2(whh[32 +  c4 * 4 + pp], u.p[pp], s2);
                s3 = dot2(whh[48 +  c4 * 4 + pp], u.p[pp], s3);
            }
        }
        #pragma unroll
        for (int c4 = 0; c4 < 2; ++c4) {
            union { h8v v; h2v p[4]; } u;
            u.v = xp8[c4];
            #pragma unroll
            for (int pp = 0; pp < 4; ++pp) {
                s0 = dot2(wih[      c4 * 4 + pp], u.p[pp], s0);
                s1 = dot2(wih[ 8 +  c4 * 4 + pp], u.p[pp], s1);
                s2 = dot2(wih[16 +  c4 * 4 + pp], u.p[pp], s2);
                s3 = dot2(wih[24 +  c4 * 4 + pp], u.p[pp], s3);
            }
        }

        // ---- quad allreduce (h pre-masked -> no dm in dot path) ----
        s0 = quad_allreduce(s0);
        s1 = quad_allreduce(s1);
        s2 = quad_allreduce(s2);
        s3 = quad_allreduce(s3);

        // ---- lane qq activates its own gate, then quad-broadcast ----
        const float s01 = (qq & 1) ? s1 : s0;
        const float s23 = (qq & 1) ? s3 : s2;
        const float gs  = ((qq & 2) ? s23 : s01) + bias_own;
        const float av  = (qq == 2) ? tanh_f(gs) : sigm(gs);
        const float ai  = dpp_mov<0x00>(av);
        const float af  = dpp_mov<0x55>(av);
        const float ag  = dpp_mov<0xAA>(av);
        const float ao  = dpp_mov<0xFF>(av);

        // ---- cell update, replicated (bit-identical) in quad ----
        const float dm = smask[t];
        const float cn = af * (c_reg * dm) + ai * ag;
        c_reg = cn;
        const float hn = ao * tanh_f(cn);

        if (wid == 0) {
            // counted wait BEFORE this wave's store: proves x_{t+2} landed.
            asm volatile("s_waitcnt vmcnt(1)" ::: "memory");
        }
        if (qq == 0) {
            const float smn = smask[(t + 1 < T_STEPS) ? (t + 1) : (T_STEPS - 1)];
            reinterpret_cast<_Float16*>(h16[wb])[j] = (_Float16)(hn * smn);
            hs[((size_t)t * B_ENV + b) * H_DIM + j] = hn;   // stays in flight
        }
        sync_lds();   // single barrier: h_t, x16_{t+1}, x_{t+2} all published
    }
}

// In-place row projection: out[r,:] = out_row @ W_hid^T + b_hid.
// 1024 blocks x 256 threads; block owns 128 rows (disjoint -> in-place safe).
#define PADK 68
__global__ __launch_bounds__(256)
void ppo_proj(const float* __restrict__ W_hid,   // [H,H]
              const float* __restrict__ b_hid,   // [H]
              float* __restrict__ out)           // [T*B, H] in-place
{
    __shared__ h2v wl[H_DIM][PADK];
    __shared__ h2v hl[H_DIM][PADK];
    const int tid = threadIdx.x;
    const int rg  = tid >> 4;
    const int cg  = tid & 15;

    const size_t r0 = (size_t)blockIdx.x * H_DIM;

    #pragma unroll
    for (int i = 0; i < 16; ++i) {
        const int idx = tid + 256 * i;
        const int r = idx >> 5, cc = idx & 31;
        f4v v = *reinterpret_cast<const f4v*>(W_hid + 4 * (size_t)idx);
        wl[r][2 * cc]     = pack16(v.x, v.y);
        wl[r][2 * cc + 1] = pack16(v.z, v.w);
    }
    #pragma unroll
    for (int i = 0; i < 16; ++i) {
        const int idx = tid + 256 * i;
        const int r = idx >> 5, cc = idx & 31;
        f4v v = *reinterpret_cast<const f4v*>(out + (r0 + r) * H_DIM + 4 * cc);
        hl[r][2 * cc]     = pack16(v.x, v.y);
        hl[r][2 * cc + 1] = pack16(v.z, v.w);
    }
    float bcol[8];
    #pragma unroll
    for (int jj = 0; jj < 8; ++jj) bcol[jj] = b_hid[cg + 16 * jj];
    __syncthreads();

    float acc[8][8];
    #pragma unroll
    for (int i = 0; i < 8; ++i)
        #pragma unroll
        for (int jj = 0; jj < 8; ++jj) acc[i][jj] = 0.f;

    for (int kq = 0; kq < 16; ++kq) {
        union { h8v v; h2v p[4]; } hv[8], wv[8];
        #pragma unroll
        for (int i = 0; i < 8; ++i)
            hv[i].v = *reinterpret_cast<const h8v*>(&hl[rg * 8 + i][4 * kq]);
        #pragma unroll
        for (int jj = 0; jj < 8; ++jj)
            wv[jj].v = *reinterpret_cast<const h8v*>(&wl[cg + 16 * jj][4 * kq]);
        #pragma unroll
        for (int i = 0; i < 8; ++i)
            #pragma unroll
            for (int jj = 0; jj < 8; ++jj) {
                acc[i][jj] = dot2(hv[i].p[0], wv[jj].p[0], acc[i][jj]);
                acc[i][jj] = dot2(hv[i].p[1], wv[jj].p[1], acc[i][jj]);
                acc[i][jj] = dot2(hv[i].p[2], wv[jj].p[2], acc[i][jj]);
                acc[i][jj] = dot2(hv[i].p[3], wv[jj].p[3], acc[i][jj]);
            }
    }

    #pragma unroll
    for (int i = 0; i < 8; ++i)
        #pragma unroll
        for (int jj = 0; jj < 8; ++jj)
            out[(r0 + rg * 8 + i) * H_DIM + cg + 16 * jj] = acc[i][jj] + bcol[jj];
}

extern "C" void kernel_launch(void* const* d_in, const int* in_sizes, int n_in,
                              void* d_out, int out_size, void* d_ws, size_t ws_size,
                              hipStream_t stream) {
    const float* x     = (const float*)d_in[0];
    const float* done  = (const float*)d_in[1];
    const float* h0    = (const float*)d_in[2];
    const float* c0    = (const float*)d_in[3];
    const float* W_ih  = (const float*)d_in[4];
    const float* b_ih  = (const float*)d_in[5];
    const float* W_hh  = (const float*)d_in[6];
    const float* b_hh  = (const float*)d_in[7];
    const float* W_hid = (const float*)d_in[8];
    const float* b_hid = (const float*)d_in[9];
    float* out = (float*)d_out;
    (void)d_ws; (void)ws_size; (void)out_size; (void)n_in; (void)in_sizes;

    hipLaunchKernelGGL(ppo_lstm_scan, dim3(B_ENV), dim3(512), 0, stream,
                       x, done, h0, c0, W_ih, b_ih, W_hh, b_hh, out);
    hipLaunchKernelGGL(ppo_proj, dim3((T_STEPS * B_ENV) / H_DIM), dim3(256), 0, stream,
                       W_hid, b_hid, out);
}